// Round 7
// baseline (132.196 us; speedup 1.0000x reference)
//
#include <hip/hip_runtime.h>
#include <hip/hip_bf16.h>

// Tree-MLP via bf16 MFMA (16x16x32), fp32 accumulate. v7: max-TLP.
//  - R6 counters: VGPR=64, MfmaUtil 11%, VALUBusy 35%, occupancy low,
//    HBM 2 TB/s -> latency-bound, waves stalled ~95%. VGPR=64 supports
//    8 waves/SIMD; previous grid only gave 4.
//  - ONE change vs v5: grid 2048 = 8 blocks/CU resident (32 waves/CU),
//    __launch_bounds__(256,8) to pin VGPR <= 64. 4 tiles/wave, no tail.
//  - body unchanged: swapped-product MFMA tree, DFS eval, bf16-packed
//    biases, 2-deep prefetch, nt stores.

typedef __attribute__((ext_vector_type(8))) short bf16x8;   // 8 bf16 = 4 VGPRs
typedef __attribute__((ext_vector_type(4))) short bf16x4;   // 4 bf16 = 2 VGPRs
typedef __attribute__((ext_vector_type(4))) float f32x4;    // 4 fp32

__device__ __forceinline__ short bfr(float f) {
  return (short)__builtin_bit_cast(unsigned short, __float2bfloat16(f));
}
__device__ __forceinline__ float bf2f(short s) {
  unsigned u = ((unsigned)(unsigned short)s) << 16;
  return __builtin_bit_cast(float, u);
}
__device__ __forceinline__ float relu_(float a) { return fmaxf(a, 0.0f); }
__device__ __forceinline__ f32x4 unpk(bf16x4 p) {
  f32x4 c;
#pragma unroll
  for (int r = 0; r < 4; ++r) c[r] = bf2f(p[r]);
  return c;
}

__global__ __launch_bounds__(256, 8) void tree_mlp_mfma7(
    const float* __restrict__ x,
    const float* __restrict__ W1, const float* __restrict__ b1,
    const float* __restrict__ W2, const float* __restrict__ b2,
    const float* __restrict__ W3, const float* __restrict__ b3,
    const float* __restrict__ W4, const float* __restrict__ b4,
    float* __restrict__ out, int ntiles) {
  const int lane = threadIdx.x & 63;
  const int n = lane & 15;   // output feature row / sample col
  const int g = lane >> 4;   // lane group 0..3

  const int wpb = blockDim.x >> 6;
  const int gw = blockIdx.x * wpb + (threadIdx.x >> 6);
  const int nw = gridDim.x * wpb;

  // ---------------- weight fragments (loop-invariant) ----------------
  bf16x8 w1f[8];
#pragma unroll
  for (int i = 0; i < 8; ++i) {
    bf16x8 f;
#pragma unroll
    for (int j = 0; j < 8; ++j) f[j] = (short)0;
#pragma unroll
    for (int j = 0; j < 4; ++j) {
      int k = 4 * g + j;
      float v = 0.0f;
      if (k == 2 * i)     v = W1[i * 32 + n];
      if (k == 2 * i + 1) v = W1[i * 32 + 16 + n];
      f[j] = bfr(v);
    }
    if (g == 0) f[4] = bfr(b1[i * 16 + n]);   // L1 bias in k==16 slot
    w1f[i] = f;
  }
  bf16x8 w2f[4]; bf16x4 c2p[4];
#pragma unroll
  for (int i = 0; i < 4; ++i) {
    bf16x8 f;
#pragma unroll
    for (int j = 0; j < 4; ++j) f[j]     = bfr(W2[i * 512 + (4 * g + j) * 16 + n]);
#pragma unroll
    for (int j = 0; j < 4; ++j) f[4 + j] = bfr(W2[i * 512 + (16 + 4 * g + j) * 16 + n]);
    w2f[i] = f;
#pragma unroll
    for (int r = 0; r < 4; ++r) c2p[i][r] = bfr(b2[i * 16 + 4 * g + r]);
  }
  bf16x8 w3f[2]; bf16x4 c3p[2];
#pragma unroll
  for (int i = 0; i < 2; ++i) {
    bf16x8 f;
#pragma unroll
    for (int j = 0; j < 4; ++j) f[j]     = bfr(W3[i * 512 + (4 * g + j) * 16 + n]);
#pragma unroll
    for (int j = 0; j < 4; ++j) f[4 + j] = bfr(W3[i * 512 + (16 + 4 * g + j) * 16 + n]);
    w3f[i] = f;
#pragma unroll
    for (int r = 0; r < 4; ++r) c3p[i][r] = bfr(b3[i * 16 + 4 * g + r]);
  }
  bf16x8 w4f; bf16x4 c4p;
  {
    bf16x8 f;
#pragma unroll
    for (int j = 0; j < 4; ++j) f[j]     = bfr(W4[(4 * g + j) * 16 + n]);
#pragma unroll
    for (int j = 0; j < 4; ++j) f[4 + j] = bfr(W4[(16 + 4 * g + j) * 16 + n]);
    w4f = f;
#pragma unroll
    for (int r = 0; r < 4; ++r) c4p[r] = bfr(b4[4 * g + r]);
  }

  const short bias_slot = (g == 0) ? bfr(1.0f) : (short)0;
  const f32x4* __restrict__ xf = reinterpret_cast<const f32x4*>(x);
  f32x4* __restrict__ of = reinterpret_cast<f32x4*>(out);

  int t = gw;
  if (t >= ntiles) return;

  // lane (n,g) owns sample row 16t+n, features [4g,4g+3] -> one 16B load
  f32x4 xa = xf[(size_t)(t * 16 + n) * 4 + g];
  f32x4 xb1 = xa;
  if (t + nw < ntiles) xb1 = xf[(size_t)((t + nw) * 16 + n) * 4 + g];

  for (; t < ntiles; t += nw) {
    f32x4 xc = xb1;
    if (t + 2 * nw < ntiles) xc = xf[(size_t)((t + 2 * nw) * 16 + n) * 4 + g];

    // level-1 B fragment: x^T with constant-1 bias feature at k==16
    bf16x8 xbf;
    xbf[0] = bfr(xa[0]); xbf[1] = bfr(xa[1]);
    xbf[2] = bfr(xa[2]); xbf[3] = bfr(xa[3]);
    xbf[4] = bias_slot; xbf[5] = 0; xbf[6] = 0; xbf[7] = 0;

    const f32x4 zero = {0.f, 0.f, 0.f, 0.f};

    // DFS evaluation: at most 2 of each level's accumulators live at once.
    f32x4 a2_0, a2_1, a3_0, a3_1;

#pragma unroll
    for (int half = 0; half < 2; ++half) {
#pragma unroll
      for (int q = 0; q < 2; ++q) {
        const int li = 4 * half + 2 * q;
        f32x4 aL = __builtin_amdgcn_mfma_f32_16x16x32_bf16(w1f[li],     xbf, zero, 0, 0, 0);
        f32x4 aR = __builtin_amdgcn_mfma_f32_16x16x32_bf16(w1f[li + 1], xbf, zero, 0, 0, 0);
        bf16x8 hb;
#pragma unroll
        for (int r = 0; r < 4; ++r) {
          hb[r]     = bfr(relu_(aL[r]));
          hb[4 + r] = bfr(relu_(aR[r]));
        }
        const int l2i = 2 * half + q;
        f32x4 acc = __builtin_amdgcn_mfma_f32_16x16x32_bf16(w2f[l2i], hb, unpk(c2p[l2i]), 0, 0, 0);
        if (q == 0) a2_0 = acc; else a2_1 = acc;
      }
      bf16x8 hb3;
#pragma unroll
      for (int r = 0; r < 4; ++r) {
        hb3[r]     = bfr(relu_(a2_0[r]));
        hb3[4 + r] = bfr(relu_(a2_1[r]));
      }
      f32x4 acc3 = __builtin_amdgcn_mfma_f32_16x16x32_bf16(w3f[half], hb3, unpk(c3p[half]), 0, 0, 0);
      if (half == 0) a3_0 = acc3; else a3_1 = acc3;
    }

    bf16x8 hb4;
#pragma unroll
    for (int r = 0; r < 4; ++r) {
      hb4[r]     = bfr(relu_(a3_0[r]));
      hb4[4 + r] = bfr(relu_(a3_1[r]));
    }
    f32x4 a4 = __builtin_amdgcn_mfma_f32_16x16x32_bf16(w4f, hb4, unpk(c4p), 0, 0, 0);

    f32x4 o;
#pragma unroll
    for (int r = 0; r < 4; ++r) o[r] = relu_(a4[r]);
    __builtin_nontemporal_store(o, &of[(size_t)(t * 16 + n) * 4 + g]);

    xa = xb1;
    xb1 = xc;
  }
}

extern "C" void kernel_launch(void* const* d_in, const int* in_sizes, int n_in,
                              void* d_out, int out_size, void* d_ws, size_t ws_size,
                              hipStream_t stream) {
  const float* x  = (const float*)d_in[0];
  const float* W1 = (const float*)d_in[1];
  const float* b1 = (const float*)d_in[2];
  const float* W2 = (const float*)d_in[3];
  const float* b2 = (const float*)d_in[4];
  const float* W3 = (const float*)d_in[5];
  const float* b3 = (const float*)d_in[6];
  const float* W4 = (const float*)d_in[7];
  const float* b4 = (const float*)d_in[8];
  float* out = (float*)d_out;

  const int ntiles = in_sizes[0] / 256;   // 16 samples x 16 features per tile
  const int block = 256;                  // 4 waves/block
  const int grid = 2048;                  // exactly 8 blocks/CU = 32 waves/CU
  tree_mlp_mfma7<<<grid, block, 0, stream>>>(x, W1, b1, W2, b2, W3, b3, W4, b4,
                                             out, ntiles);
}

// Round 8
// 29.148 us; speedup vs baseline: 4.5353x; 4.5353x over previous
//
#include <hip/hip_runtime.h>
#include <hip/hip_bf16.h>

// Tree-MLP via bf16 MFMA (16x16x32), fp32 accumulate. v8: counted-vmcnt pipeline.
//  - Diagnosis: v3-v7 all pinned at ~24us because the loop-tail register
//    rotation (xa=xb1; xb1=xc) forces a wait on the NEWEST load each
//    iteration (drain, not counted). Loaded-latency is queue-proportional,
//    so extra waves/ILP changed nothing (R4/R5 neutral, R6 counters: all
//    pipes <40%, waves stalled ~90%).
//  - Fix: 8 consecutive tiles per wave, depth-4 rolling window in NAMED
//    registers: copy slot out -> reissue slot for tile k+4 -> compute.
//    Compiler's auto-waitcnt is then counted (3 younger loads in flight),
//    so each wave waits only for a ~4-tile-old load: memory stays ahead.
//  - grid 1024 = exactly 4 blocks/CU, 16 waves/CU, no tail.
//    VGPR ~123 < 128 cap of __launch_bounds__(256,4) (R7 lesson: (256,8)
//    spilled catastrophically; R6 proved base body fits 64).

typedef __attribute__((ext_vector_type(8))) short bf16x8;   // 8 bf16 = 4 VGPRs
typedef __attribute__((ext_vector_type(4))) short bf16x4;   // 4 bf16 = 2 VGPRs
typedef __attribute__((ext_vector_type(4))) float f32x4;    // 4 fp32

__device__ __forceinline__ short bfr(float f) {
  return (short)__builtin_bit_cast(unsigned short, __float2bfloat16(f));
}
__device__ __forceinline__ float bf2f(short s) {
  unsigned u = ((unsigned)(unsigned short)s) << 16;
  return __builtin_bit_cast(float, u);
}
__device__ __forceinline__ float relu_(float a) { return fmaxf(a, 0.0f); }
__device__ __forceinline__ f32x4 unpk(bf16x4 p) {
  f32x4 c;
#pragma unroll
  for (int r = 0; r < 4; ++r) c[r] = bf2f(p[r]);
  return c;
}

__global__ __launch_bounds__(256, 4) void tree_mlp_mfma8(
    const float* __restrict__ x,
    const float* __restrict__ W1, const float* __restrict__ b1,
    const float* __restrict__ W2, const float* __restrict__ b2,
    const float* __restrict__ W3, const float* __restrict__ b3,
    const float* __restrict__ W4, const float* __restrict__ b4,
    float* __restrict__ out, int ntiles) {
  const int lane = threadIdx.x & 63;
  const int n = lane & 15;   // output feature row / sample col
  const int g = lane >> 4;   // lane group 0..3

  const int wpb = blockDim.x >> 6;
  const int gw = blockIdx.x * wpb + (threadIdx.x >> 6);
  const int nw = gridDim.x * wpb;

  // ---------------- weight fragments (loop-invariant) ----------------
  bf16x8 w1f[8];
#pragma unroll
  for (int i = 0; i < 8; ++i) {
    bf16x8 f;
#pragma unroll
    for (int j = 0; j < 8; ++j) f[j] = (short)0;
#pragma unroll
    for (int j = 0; j < 4; ++j) {
      int k = 4 * g + j;
      float v = 0.0f;
      if (k == 2 * i)     v = W1[i * 32 + n];
      if (k == 2 * i + 1) v = W1[i * 32 + 16 + n];
      f[j] = bfr(v);
    }
    if (g == 0) f[4] = bfr(b1[i * 16 + n]);   // L1 bias in k==16 slot
    w1f[i] = f;
  }
  bf16x8 w2f[4]; bf16x4 c2p[4];
#pragma unroll
  for (int i = 0; i < 4; ++i) {
    bf16x8 f;
#pragma unroll
    for (int j = 0; j < 4; ++j) f[j]     = bfr(W2[i * 512 + (4 * g + j) * 16 + n]);
#pragma unroll
    for (int j = 0; j < 4; ++j) f[4 + j] = bfr(W2[i * 512 + (16 + 4 * g + j) * 16 + n]);
    w2f[i] = f;
#pragma unroll
    for (int r = 0; r < 4; ++r) c2p[i][r] = bfr(b2[i * 16 + 4 * g + r]);
  }
  bf16x8 w3f[2]; bf16x4 c3p[2];
#pragma unroll
  for (int i = 0; i < 2; ++i) {
    bf16x8 f;
#pragma unroll
    for (int j = 0; j < 4; ++j) f[j]     = bfr(W3[i * 512 + (4 * g + j) * 16 + n]);
#pragma unroll
    for (int j = 0; j < 4; ++j) f[4 + j] = bfr(W3[i * 512 + (16 + 4 * g + j) * 16 + n]);
    w3f[i] = f;
#pragma unroll
    for (int r = 0; r < 4; ++r) c3p[i][r] = bfr(b3[i * 16 + 4 * g + r]);
  }
  bf16x8 w4f; bf16x4 c4p;
  {
    bf16x8 f;
#pragma unroll
    for (int j = 0; j < 4; ++j) f[j]     = bfr(W4[(4 * g + j) * 16 + n]);
#pragma unroll
    for (int j = 0; j < 4; ++j) f[4 + j] = bfr(W4[(16 + 4 * g + j) * 16 + n]);
    w4f = f;
#pragma unroll
    for (int r = 0; r < 4; ++r) c4p[r] = bfr(b4[4 * g + r]);
  }

  const short bias_slot = (g == 0) ? bfr(1.0f) : (short)0;
  const f32x4* __restrict__ xf = reinterpret_cast<const f32x4*>(x);
  f32x4* __restrict__ of = reinterpret_cast<f32x4*>(out);
  const int lo = n * 4 + g;   // lane's 16B slot within a 1KB tile

  const int base = gw * 8;
  const int bstr = nw * 8;

  for (int b = base; b < ntiles; b += bstr) {
    // ---- fill depth-4 window ----
    f32x4 xw0, xw1, xw2, xw3;
    xw0 = xf[(size_t)(b) * 64 + lo];
    if (b + 1 < ntiles) xw1 = xf[(size_t)(b + 1) * 64 + lo];
    if (b + 2 < ntiles) xw2 = xf[(size_t)(b + 2) * 64 + lo];
    if (b + 3 < ntiles) xw3 = xf[(size_t)(b + 3) * 64 + lo];

    // ---- one tile: copy slot out, reissue slot, compute, store ----
#define TILE_STEP(K, SLOT, PREFETCH_STMT)                                      \
    if (b + (K) < ntiles) {                                                    \
      f32x4 xv = SLOT;                                                         \
      PREFETCH_STMT;                                                           \
      bf16x8 xbf;                                                              \
      xbf[0] = bfr(xv[0]); xbf[1] = bfr(xv[1]);                                \
      xbf[2] = bfr(xv[2]); xbf[3] = bfr(xv[3]);                                \
      xbf[4] = bias_slot; xbf[5] = 0; xbf[6] = 0; xbf[7] = 0;                  \
      const f32x4 zero = {0.f, 0.f, 0.f, 0.f};                                 \
      f32x4 a2_0, a2_1, a3_0, a3_1;                                            \
      _Pragma("unroll")                                                        \
      for (int half = 0; half < 2; ++half) {                                   \
        _Pragma("unroll")                                                      \
        for (int q = 0; q < 2; ++q) {                                          \
          const int li = 4 * half + 2 * q;                                     \
          f32x4 aL = __builtin_amdgcn_mfma_f32_16x16x32_bf16(w1f[li],     xbf, zero, 0, 0, 0); \
          f32x4 aR = __builtin_amdgcn_mfma_f32_16x16x32_bf16(w1f[li + 1], xbf, zero, 0, 0, 0); \
          bf16x8 hb;                                                           \
          _Pragma("unroll")                                                    \
          for (int r = 0; r < 4; ++r) {                                        \
            hb[r]     = bfr(relu_(aL[r]));                                     \
            hb[4 + r] = bfr(relu_(aR[r]));                                     \
          }                                                                    \
          const int l2i = 2 * half + q;                                        \
          f32x4 acc = __builtin_amdgcn_mfma_f32_16x16x32_bf16(w2f[l2i], hb, unpk(c2p[l2i]), 0, 0, 0); \
          if (q == 0) a2_0 = acc; else a2_1 = acc;                             \
        }                                                                      \
        bf16x8 hb3;                                                            \
        _Pragma("unroll")                                                      \
        for (int r = 0; r < 4; ++r) {                                          \
          hb3[r]     = bfr(relu_(a2_0[r]));                                    \
          hb3[4 + r] = bfr(relu_(a2_1[r]));                                    \
        }                                                                      \
        f32x4 acc3 = __builtin_amdgcn_mfma_f32_16x16x32_bf16(w3f[half], hb3, unpk(c3p[half]), 0, 0, 0); \
        if (half == 0) a3_0 = acc3; else a3_1 = acc3;                          \
      }                                                                        \
      bf16x8 hb4;                                                              \
      _Pragma("unroll")                                                        \
      for (int r = 0; r < 4; ++r) {                                            \
        hb4[r]     = bfr(relu_(a3_0[r]));                                      \
        hb4[4 + r] = bfr(relu_(a3_1[r]));                                      \
      }                                                                        \
      f32x4 a4 = __builtin_amdgcn_mfma_f32_16x16x32_bf16(w4f, hb4, unpk(c4p), 0, 0, 0); \
      f32x4 o;                                                                 \
      _Pragma("unroll")                                                        \
      for (int r = 0; r < 4; ++r) o[r] = relu_(a4[r]);                         \
      __builtin_nontemporal_store(o, &of[(size_t)(b + (K)) * 64 + lo]);        \
    }

    TILE_STEP(0, xw0, if (b + 4 < ntiles) xw0 = xf[(size_t)(b + 4) * 64 + lo])
    TILE_STEP(1, xw1, if (b + 5 < ntiles) xw1 = xf[(size_t)(b + 5) * 64 + lo])
    TILE_STEP(2, xw2, if (b + 6 < ntiles) xw2 = xf[(size_t)(b + 6) * 64 + lo])
    TILE_STEP(3, xw3, if (b + 7 < ntiles) xw3 = xf[(size_t)(b + 7) * 64 + lo])
    TILE_STEP(4, xw0, )
    TILE_STEP(5, xw1, )
    TILE_STEP(6, xw2, )
    TILE_STEP(7, xw3, )
#undef TILE_STEP
  }
}

extern "C" void kernel_launch(void* const* d_in, const int* in_sizes, int n_in,
                              void* d_out, int out_size, void* d_ws, size_t ws_size,
                              hipStream_t stream) {
  const float* x  = (const float*)d_in[0];
  const float* W1 = (const float*)d_in[1];
  const float* b1 = (const float*)d_in[2];
  const float* W2 = (const float*)d_in[3];
  const float* b2 = (const float*)d_in[4];
  const float* W3 = (const float*)d_in[5];
  const float* b3 = (const float*)d_in[6];
  const float* W4 = (const float*)d_in[7];
  const float* b4 = (const float*)d_in[8];
  float* out = (float*)d_out;

  const int ntiles = in_sizes[0] / 256;   // 16 samples x 16 features per tile
  const int block = 256;                  // 4 waves/block
  const int grid = 1024;                  // exactly 4 blocks/CU, 8 tiles/wave
  tree_mlp_mfma8<<<grid, block, 0, stream>>>(x, W1, b1, W2, b2, W3, b3, W4, b4,
                                             out, ntiles);
}

// Round 9
// 24.873 us; speedup vs baseline: 5.3149x; 1.1719x over previous
//
#include <hip/hip_runtime.h>
#include <hip/hip_bf16.h>

// Tree-MLP via bf16 MFMA (16x16x32), fp32 accumulate. v9: VALU-diet.
//  - R6 counters decoded: ~350 VALU instrs/tile (VALUBusy 35% over 2006
//    cyc/tile-SIMD) -> scalar __float2bfloat16 (~5 ops + v_cmp each, x60/tile)
//    dominates issue. Fix: v_cvt_pk_bf16_f32 inline asm (1 op per 2 values,
//    RTNE, packs straight into the bf16x8 dword layout).
//  - TPI=2 chain interleave (R4 retry, de-confounded: f32 biases, no unpk):
//    6 independent MFMA<->cvt chains per SIMD cover residual chain latency.
//  - (256,3), grid 768 = 3 blocks/CU; nt stores; 1-supertile prefetch.

typedef __attribute__((ext_vector_type(8))) short bf16x8;     // 8 bf16 = 4 VGPRs
typedef __attribute__((ext_vector_type(4))) float f32x4;      // 4 fp32
typedef __attribute__((ext_vector_type(4))) unsigned u32x4;   // 4 dwords

__device__ __forceinline__ short bfr(float f) {
  return (short)__builtin_bit_cast(unsigned short, __float2bfloat16(f));
}
__device__ __forceinline__ float relu_(float a) { return fmaxf(a, 0.0f); }

// packed RTNE f32x2 -> bf16x2 (gfx950 v_cvt_pk_bf16_f32): lo=cvt(a), hi=cvt(b)
__device__ __forceinline__ unsigned pk2(float a, float b) {
  unsigned r;
  asm("v_cvt_pk_bf16_f32 %0, %1, %2" : "=v"(r) : "v"(a), "v"(b));
  return r;
}
// relu + pack two f32x4 accumulators into one MFMA B-operand fragment
__device__ __forceinline__ bf16x8 pack8(f32x4 L, f32x4 R) {
  u32x4 u;
  u[0] = pk2(relu_(L[0]), relu_(L[1]));
  u[1] = pk2(relu_(L[2]), relu_(L[3]));
  u[2] = pk2(relu_(R[0]), relu_(R[1]));
  u[3] = pk2(relu_(R[2]), relu_(R[3]));
  return __builtin_bit_cast(bf16x8, u);
}

__global__ __launch_bounds__(256, 3) void tree_mlp_mfma9(
    const float* __restrict__ x,
    const float* __restrict__ W1, const float* __restrict__ b1,
    const float* __restrict__ W2, const float* __restrict__ b2,
    const float* __restrict__ W3, const float* __restrict__ b3,
    const float* __restrict__ W4, const float* __restrict__ b4,
    float* __restrict__ out, int ntiles) {
  const int lane = threadIdx.x & 63;
  const int n = lane & 15;   // output feature row / sample col
  const int g = lane >> 4;   // lane group 0..3

  const int wpb = blockDim.x >> 6;
  const int gw = blockIdx.x * wpb + (threadIdx.x >> 6);
  const int nw = gridDim.x * wpb;

  // ---------------- weight fragments (loop-invariant) ----------------
  bf16x8 w1f[8];
#pragma unroll
  for (int i = 0; i < 8; ++i) {
    bf16x8 f;
#pragma unroll
    for (int j = 0; j < 8; ++j) f[j] = (short)0;
#pragma unroll
    for (int j = 0; j < 4; ++j) {
      int k = 4 * g + j;
      float v = 0.0f;
      if (k == 2 * i)     v = W1[i * 32 + n];
      if (k == 2 * i + 1) v = W1[i * 32 + 16 + n];
      f[j] = bfr(v);
    }
    if (g == 0) f[4] = bfr(b1[i * 16 + n]);   // L1 bias in k==16 slot
    w1f[i] = f;
  }
  bf16x8 w2f[4]; f32x4 c2[4];
#pragma unroll
  for (int i = 0; i < 4; ++i) {
    bf16x8 f;
#pragma unroll
    for (int j = 0; j < 4; ++j) f[j]     = bfr(W2[i * 512 + (4 * g + j) * 16 + n]);
#pragma unroll
    for (int j = 0; j < 4; ++j) f[4 + j] = bfr(W2[i * 512 + (16 + 4 * g + j) * 16 + n]);
    w2f[i] = f;
#pragma unroll
    for (int r = 0; r < 4; ++r) c2[i][r] = b2[i * 16 + 4 * g + r];
  }
  bf16x8 w3f[2]; f32x4 c3[2];
#pragma unroll
  for (int i = 0; i < 2; ++i) {
    bf16x8 f;
#pragma unroll
    for (int j = 0; j < 4; ++j) f[j]     = bfr(W3[i * 512 + (4 * g + j) * 16 + n]);
#pragma unroll
    for (int j = 0; j < 4; ++j) f[4 + j] = bfr(W3[i * 512 + (16 + 4 * g + j) * 16 + n]);
    w3f[i] = f;
#pragma unroll
    for (int r = 0; r < 4; ++r) c3[i][r] = b3[i * 16 + 4 * g + r];
  }
  bf16x8 w4f; f32x4 c4;
  {
    bf16x8 f;
#pragma unroll
    for (int j = 0; j < 4; ++j) f[j]     = bfr(W4[(4 * g + j) * 16 + n]);
#pragma unroll
    for (int j = 0; j < 4; ++j) f[4 + j] = bfr(W4[(16 + 4 * g + j) * 16 + n]);
    w4f = f;
#pragma unroll
    for (int r = 0; r < 4; ++r) c4[r] = b4[4 * g + r];
  }

  const unsigned bias_dw = (g == 0) ? 0x00003F80u : 0u;   // bf16(1.0) in k==16
  const f32x4* __restrict__ xf = reinterpret_cast<const f32x4*>(x);
  f32x4* __restrict__ of = reinterpret_cast<f32x4*>(out);

  const int nsuper = ntiles >> 1;   // 2 tiles per supertile
  int s = gw;
  if (s >= nsuper) return;

  // lane (n,g) owns sample row 16t+n, features [4g,4g+3] -> one 16B load
  f32x4 xa0 = xf[(size_t)((2 * s)     * 16 + n) * 4 + g];
  f32x4 xa1 = xf[(size_t)((2 * s + 1) * 16 + n) * 4 + g];

  for (; s < nsuper; s += nw) {
    const int sn = s + nw;
    f32x4 xn0 = xa0, xn1 = xa1;
    if (sn < nsuper) {   // prefetch next supertile's 2 tiles at loop top
      xn0 = xf[(size_t)((2 * sn)     * 16 + n) * 4 + g];
      xn1 = xf[(size_t)((2 * sn + 1) * 16 + n) * 4 + g];
    }

    // level-1 B fragments: packed x^T with constant-1 bias feature at k==16
    bf16x8 xb[2];
#pragma unroll
    for (int u = 0; u < 2; ++u) {
      const f32x4 xv = (u == 0) ? xa0 : xa1;
      u32x4 q;
      q[0] = pk2(xv[0], xv[1]);
      q[1] = pk2(xv[2], xv[3]);
      q[2] = bias_dw;
      q[3] = 0u;
      xb[u] = __builtin_bit_cast(bf16x8, q);
    }

    const f32x4 zero = {0.f, 0.f, 0.f, 0.f};

    // two independent chains (u=0,1) interleaved at every stage
    f32x4 a2[2][4];
#pragma unroll
    for (int i = 0; i < 4; ++i) {
#pragma unroll
      for (int u = 0; u < 2; ++u) {
        f32x4 aL = __builtin_amdgcn_mfma_f32_16x16x32_bf16(w1f[2 * i],     xb[u], zero, 0, 0, 0);
        f32x4 aR = __builtin_amdgcn_mfma_f32_16x16x32_bf16(w1f[2 * i + 1], xb[u], zero, 0, 0, 0);
        a2[u][i] = __builtin_amdgcn_mfma_f32_16x16x32_bf16(w2f[i], pack8(aL, aR), c2[i], 0, 0, 0);
      }
    }

    f32x4 a3[2][2];
#pragma unroll
    for (int i = 0; i < 2; ++i) {
#pragma unroll
      for (int u = 0; u < 2; ++u) {
        a3[u][i] = __builtin_amdgcn_mfma_f32_16x16x32_bf16(
            w3f[i], pack8(a2[u][2 * i], a2[u][2 * i + 1]), c3[i], 0, 0, 0);
      }
    }

    f32x4 a4[2];
#pragma unroll
    for (int u = 0; u < 2; ++u)
      a4[u] = __builtin_amdgcn_mfma_f32_16x16x32_bf16(
          w4f, pack8(a3[u][0], a3[u][1]), c4, 0, 0, 0);

#pragma unroll
    for (int u = 0; u < 2; ++u) {
      f32x4 o;
#pragma unroll
      for (int r = 0; r < 4; ++r) o[r] = relu_(a4[u][r]);
      __builtin_nontemporal_store(o, &of[(size_t)((2 * s + u) * 16 + n) * 4 + g]);
    }

    xa0 = xn0;
    xa1 = xn1;
  }
}

extern "C" void kernel_launch(void* const* d_in, const int* in_sizes, int n_in,
                              void* d_out, int out_size, void* d_ws, size_t ws_size,
                              hipStream_t stream) {
  const float* x  = (const float*)d_in[0];
  const float* W1 = (const float*)d_in[1];
  const float* b1 = (const float*)d_in[2];
  const float* W2 = (const float*)d_in[3];
  const float* b2 = (const float*)d_in[4];
  const float* W3 = (const float*)d_in[5];
  const float* b3 = (const float*)d_in[6];
  const float* W4 = (const float*)d_in[7];
  const float* b4 = (const float*)d_in[8];
  float* out = (float*)d_out;

  const int ntiles = in_sizes[0] / 256;   // 16 samples x 16 features per tile
  const int block = 256;                  // 4 waves/block
  const int grid = 768;                   // 3 blocks/CU resident
  tree_mlp_mfma9<<<grid, block, 0, stream>>>(x, W1, b1, W2, b2, W3, b3, W4, b4,
                                             out, ntiles);
}